// Round 3
// baseline (560.077 us; speedup 1.0000x reference)
//
#include <hip/hip_runtime.h>

// VectorQuantizer: z (32, 64, 4096) f32, emb (1024, 64) f32.
// For each of 131072 column-vectors of z, argmin_j ||z - emb_j||^2, output
// emb[argmin] in (BS, C, SEQ) layout.
//
// Numerics (DO NOT CHANGE — absmax 0.0 in R1/R2):
//   d = fma(-2, dot, fadd(z_sq, e_sq))
//   dot: single sequential FMA chain k=0..63 per (row, code)
//   z_sq / e_sq: numpy pairwise order for n=64 (8 accs of rounded squares,
//   r[t] init 0 then fadd — 0 + x^2 is exact — then pairwise tree)
//   argmin: strict '<', j ascending (tiles ascending, jj ascending inside)
//
// R3 restructure (perf only): R1/R2 kept zv[64] per-lane; the allocator
// refused (VGPR_Count=40 both rounds) and re-read ~256B/lane per j from
// scratch -> ~34 TB of L1 traffic = the observed 475 us. Fix: z row lives
// in LDS, only a float4 chunk is live; j-tile of 8 amortizes each LDS read
// across 8 codes and gives 8 independent FMA chains (ILP). e-chunks are
// wave-uniform -> s_load_dwordx4 (32 SGPRs live, room to pipeline).

constexpr int N_EMB = 1024;
constexpr int CDIM  = 64;
constexpr int SEQ   = 4096;
constexpr int BS    = 32;
constexpr int NROWS = BS * SEQ;   // 131072
constexpr int TPB   = 128;        // 2 waves; 128 rows per block
constexpr int JT    = 8;          // codes per j-tile
constexpr int KC    = CDIM / 4;   // 16 float4 chunks per row
constexpr int ZSTR  = 68;         // 64 + 4 pad words: stride % 32 = 4 -> b128
                                  // reads are bank-limited (8cyc min), not
                                  // serialized (stride 64 would be 4-bank)

__global__ __launch_bounds__(TPB, 4) void vq_kernel(
    const float* __restrict__ z,
    const float* __restrict__ emb,
    float* __restrict__ out)
{
    __shared__ float zt[TPB][ZSTR];
    __shared__ float esq[N_EMB];

    const int t    = threadIdx.x;
    const int row0 = blockIdx.x * TPB;     // 4096 % 128 == 0 -> one b per block
    const int b    = row0 >> 12;
    const int s0   = row0 & (SEQ - 1);

    // ---- e_sq for all codes, numpy pairwise order (8 codes per thread) ----
    for (int j = t; j < N_EMB; j += TPB) {
        const float* e = emb + j * CDIM;
        float r[8];
        #pragma unroll
        for (int q = 0; q < 8; ++q) r[q] = __fmul_rn(e[q], e[q]);
        #pragma unroll
        for (int i = 8; i < 64; i += 8) {
            #pragma unroll
            for (int q = 0; q < 8; ++q)
                r[q] = __fadd_rn(r[q], __fmul_rn(e[i + q], e[i + q]));
        }
        esq[j] = __fadd_rn(
                    __fadd_rn(__fadd_rn(r[0], r[1]), __fadd_rn(r[2], r[3])),
                    __fadd_rn(__fadd_rn(r[4], r[5]), __fadd_rn(r[6], r[7])));
    }

    // ---- stage this thread's z row into LDS + z_sq (pairwise) ----
    // lane t owns row s0+t; at fixed k, lanes read consecutive s (coalesced)
    const float* zp = z + (size_t)b * CDIM * SEQ + s0 + t;
    float r[8];
    #pragma unroll
    for (int q = 0; q < 8; ++q) r[q] = 0.0f;
    #pragma unroll
    for (int k = 0; k < CDIM; ++k) {
        const float x = zp[(size_t)k * SEQ];
        zt[t][k] = x;
        r[k & 7] = __fadd_rn(r[k & 7], __fmul_rn(x, x));  // 0 + x^2 exact
    }
    const float zsq = __fadd_rn(
                        __fadd_rn(__fadd_rn(r[0], r[1]), __fadd_rn(r[2], r[3])),
                        __fadd_rn(__fadd_rn(r[4], r[5]), __fadd_rn(r[6], r[7])));

    __syncthreads();

    // ---- scan codes in tiles of JT; kc outer, jj inner; acc[jj] keeps the
    //      exact sequential k-chain per code ----
    float dmin = INFINITY;
    int   jmin = 0;
    #pragma unroll 1
    for (int j0 = 0; j0 < N_EMB; j0 += JT) {
        const float4* ep = reinterpret_cast<const float4*>(emb + (size_t)j0 * CDIM);
        float acc[JT];
        #pragma unroll
        for (int jj = 0; jj < JT; ++jj) acc[jj] = 0.0f;

        #pragma unroll 2
        for (int kc = 0; kc < KC; ++kc) {
            const float4 zc = *reinterpret_cast<const float4*>(&zt[t][kc * 4]);
            #pragma unroll
            for (int jj = 0; jj < JT; ++jj) {
                const float4 ev = ep[jj * KC + kc];   // uniform -> s_load_dwordx4
                acc[jj] = __fmaf_rn(zc.x, ev.x, acc[jj]);
                acc[jj] = __fmaf_rn(zc.y, ev.y, acc[jj]);
                acc[jj] = __fmaf_rn(zc.z, ev.z, acc[jj]);
                acc[jj] = __fmaf_rn(zc.w, ev.w, acc[jj]);
            }
        }
        #pragma unroll
        for (int jj = 0; jj < JT; ++jj) {
            const float d = __fmaf_rn(-2.0f, acc[jj], __fadd_rn(zsq, esq[j0 + jj]));
            if (d < dmin) { dmin = d; jmin = j0 + jj; }   // strict < = first idx
        }
    }

    // ---- gather emb[jmin], scatter to (b, c, s) ----
    const float4* ej = reinterpret_cast<const float4*>(emb + (size_t)jmin * CDIM);
    float* op = out + (size_t)b * CDIM * SEQ + s0 + t;
    #pragma unroll
    for (int q = 0; q < KC; ++q) {
        const float4 v = ej[q];               // per-lane gather, emb is L2-hot
        op[(size_t)(4 * q + 0) * SEQ] = v.x;
        op[(size_t)(4 * q + 1) * SEQ] = v.y;
        op[(size_t)(4 * q + 2) * SEQ] = v.z;
        op[(size_t)(4 * q + 3) * SEQ] = v.w;
    }
}

extern "C" void kernel_launch(void* const* d_in, const int* in_sizes, int n_in,
                              void* d_out, int out_size, void* d_ws, size_t ws_size,
                              hipStream_t stream)
{
    const float* z   = (const float*)d_in[0];
    const float* emb = (const float*)d_in[1];
    float* out = (float*)d_out;

    vq_kernel<<<NROWS / TPB, TPB, 0, stream>>>(z, emb, out);   // 1024 blocks
}

// Round 6
// 172.224 us; speedup vs baseline: 3.2520x; 3.2520x over previous
//
#include <hip/hip_runtime.h>
#include <hip/hip_bf16.h>

// VectorQuantizer: z (32, 64, 4096) f32, emb (1024, 64) f32.
// argmin_j ||z - emb_j||^2 per column-vector, output emb[argmin] in (B,C,S).
//
// R6 == R5 == R4 (never ran: two GPU acquisition timeouts). Unchanged.
//
// Structure: bf16 MFMA screening + provably-sufficient exact rescore.
//   setup kernel: emb -> bf16 copy (ws), exact esq (numpy pairwise, == R1 bits),
//                 e_max.
//   main kernel, per 128-row block:
//     stage: z rows -> LDS (XOR-swizzled), exact zsq (== R1 bits), thr/row.
//     A: mfma_f32_16x16x32_bf16 scan of d' = esq - 2*dot  -> per-row min m'.
//     B: identical rescan; push (row,j) with d' <= m' + thr to LDS queue.
//        thr = 0.025*||z||*e_max + 1e-4 >= 2*|d'_approx - d'_exact| bound
//        (bf16 input rounding => |dot err| <= ~0.008*||z||*e_max; 1.5x safety)
//        -> queue provably contains the exact argmin (and all exact ties).
//     C: exact fp32 rescore of candidates with THE R1 CHAIN (bit-identical:
//        sequential k=0..63 FMA, d = fma(-2,acc,fadd(zsq,esq))); per-row
//        atomicMin on key = enc(d)<<32 | j  => numpy first-index tie-break.
//        If the queue overflowed: full 128x1024 exact rescan (always correct).
// Correctness depends only on the error bound, never on screen precision.

typedef float f32x4 __attribute__((ext_vector_type(4)));
typedef short s16x8 __attribute__((ext_vector_type(8)));

constexpr int N_EMB = 1024;
constexpr int CDIM  = 64;
constexpr int SEQ   = 4096;
constexpr int BS    = 32;
constexpr int NROWS = BS * SEQ;     // 131072
constexpr int RPB   = 128;          // rows per block -> 1024 blocks
constexpr int TPB   = 256;          // 4 waves; codes split 256/wave
constexpr int QMAX  = 1024;         // candidate queue (expect ~205/block)

// ws layout: [0,128K) bf16 emb | [128K,132K) esq f32 | [132K,+4) e_max f32
constexpr size_t WS_EBF  = 0;
constexpr size_t WS_ESQ  = 131072;
constexpr size_t WS_EMAX = 131072 + 4096;
constexpr size_t WS_NEED = WS_EMAX + 4;

__device__ __forceinline__ unsigned enc_f32(float f) {
    unsigned u = __float_as_uint(f);
    return (u & 0x80000000u) ? ~u : (u | 0x80000000u);   // order-preserving
}
__device__ __forceinline__ float dec_f32(unsigned k) {
    return __uint_as_float((k & 0x80000000u) ? (k & 0x7fffffffu) : ~k);
}
__device__ __forceinline__ short f2bf(float x) {
    __hip_bfloat16 h = __float2bfloat16(x);               // RNE
    return *reinterpret_cast<short*>(&h);
}
__device__ __forceinline__ float pair8(const float r[8]) {
    return __fadd_rn(
        __fadd_rn(__fadd_rn(r[0], r[1]), __fadd_rn(r[2], r[3])),
        __fadd_rn(__fadd_rn(r[4], r[5]), __fadd_rn(r[6], r[7])));
}

// ---------------- setup: ebf (bf16 emb), exact esq, e_max ----------------
__global__ __launch_bounds__(1024) void vq_setup(
    const float* __restrict__ emb, unsigned short* __restrict__ ebf,
    float* __restrict__ esqg, float* __restrict__ emaxp)
{
    const int t = threadIdx.x;
    // bf16 copy, 2 elems/u32, coalesced
    const float2* e2 = reinterpret_cast<const float2*>(emb);
    unsigned int* eb2 = reinterpret_cast<unsigned int*>(ebf);
    for (int it = 0; it < 32; ++it) {
        const int i = t + 1024 * it;                       // 32768 u32 total
        const float2 v = e2[i];
        eb2[i] = (unsigned)(unsigned short)f2bf(v.x)
               | ((unsigned)(unsigned short)f2bf(v.y) << 16);
    }
    // exact esq[t] — bit-identical to R1's in-kernel version
    const float* e = emb + t * CDIM;
    float r[8];
    #pragma unroll
    for (int q = 0; q < 8; ++q) r[q] = __fmul_rn(e[q], e[q]);
    #pragma unroll
    for (int i = 8; i < 64; i += 8) {
        #pragma unroll
        for (int q = 0; q < 8; ++q)
            r[q] = __fadd_rn(r[q], __fmul_rn(e[i + q], e[i + q]));
    }
    const float myesq = pair8(r);
    esqg[t] = myesq;
    // e_max = max_j ||e_j||
    __shared__ float red[1024];
    red[t] = myesq;
    __syncthreads();
    for (int s = 512; s > 0; s >>= 1) {
        if (t < s) red[t] = fmaxf(red[t], red[t + s]);
        __syncthreads();
    }
    if (t == 0) *emaxp = sqrtf(red[0]) * 1.0001f;
}

// ---------------- main ----------------
__global__ __launch_bounds__(TPB, 3) void vq_main(
    const float* __restrict__ z, const float* __restrict__ emb,
    const unsigned short* __restrict__ ebf, const float* __restrict__ esqg,
    const float* __restrict__ emaxp, float* __restrict__ out)
{
    __shared__ float zf[RPB * 64];          // 32 KB, XOR-swizzled fp32 z rows
    __shared__ float esq[N_EMB];            // 4 KB
    __shared__ float zsq[RPB];
    __shared__ float thr[RPB];
    __shared__ unsigned int rowmin[RPB];    // enc(min d') per row
    __shared__ unsigned long long keys[RPB];
    __shared__ unsigned int queue[QMAX];
    __shared__ unsigned int qcnt;

    const int t    = threadIdx.x;
    const int lane = t & 63;
    const int wv   = t >> 6;                // 0..3 (code range 256/wave)
    const int g    = lane >> 4;             // k-group / D-row group
    const int ln   = lane & 15;             // A-row (code) / B-col (z-row)
    const int row0 = blockIdx.x * RPB;
    const int b    = row0 >> 12;
    const int s0   = row0 & (SEQ - 1);

    // ---------- stage ----------
    if (t == 0) qcnt = 0;
    if (t < RPB) { rowmin[t] = 0xFFFFFFFFu; keys[t] = ~0ull; }
    if (t >= 128) {
        for (int i = t - 128; i < N_EMB; i += 128) esq[i] = esqg[i];
    } else {
        const int row = t;
        const float* zp = z + (size_t)b * CDIM * SEQ + s0 + row;
        const int swz = (row & 7) << 2;     // float-index XOR (16B granules)
        float r[8];
        #pragma unroll
        for (int q = 0; q < 8; ++q) r[q] = 0.0f;
        #pragma unroll
        for (int kb = 0; kb < 64; kb += 4) {
            f32x4 v;
            #pragma unroll
            for (int u = 0; u < 4; ++u) {
                const float x = zp[(size_t)(kb + u) * SEQ];
                v[u] = x;
                r[(kb + u) & 7] = __fadd_rn(r[(kb + u) & 7], __fmul_rn(x, x));
            }
            *reinterpret_cast<f32x4*>(&zf[(row << 6) | (kb ^ swz)]) = v;
        }
        const float zq = pair8(r);          // == R1 zsq bits (0+x^2 exact)
        zsq[row] = zq;
        thr[row] = __fmaf_rn(0.025f * (*emaxp), sqrtf(zq), 1e-4f);
    }
    __syncthreads();

    // ---------- z fragments: 8 row-tiles x 2 k-steps, held in VGPRs ----------
    s16x8 zfr[8][2];
    #pragma unroll
    for (int rt = 0; rt < 8; ++rt) {
        const int row = rt * 16 + ln;
        const int swz = (row & 7) << 2;
        #pragma unroll
        for (int ks = 0; ks < 2; ++ks) {
            const int kb = g * 8 + ks * 32;
            const f32x4 a = *reinterpret_cast<const f32x4*>(&zf[(row << 6) | (kb ^ swz)]);
            const f32x4 c = *reinterpret_cast<const f32x4*>(&zf[(row << 6) | ((kb + 4) ^ swz)]);
            s16x8 fr;
            fr[0] = f2bf(a[0]); fr[1] = f2bf(a[1]); fr[2] = f2bf(a[2]); fr[3] = f2bf(a[3]);
            fr[4] = f2bf(c[0]); fr[5] = f2bf(c[1]); fr[6] = f2bf(c[2]); fr[7] = f2bf(c[3]);
            zfr[rt][ks] = fr;
        }
    }

    const int cw = wv * 256;

    // ---------- phase A: scan, per-row approx min ----------
    float mrun[8];
    #pragma unroll
    for (int rt = 0; rt < 8; ++rt) mrun[rt] = INFINITY;

    #pragma unroll 1
    for (int q = 0; q < 4; ++q) {
        s16x8 efr[4][2];
        f32x4 eq[4];
        #pragma unroll
        for (int ct = 0; ct < 4; ++ct) {
            const int code = cw + q * 64 + ct * 16 + ln;
            const unsigned short* ep = ebf + code * 64;
            #pragma unroll
            for (int ks = 0; ks < 2; ++ks)
                efr[ct][ks] = *reinterpret_cast<const s16x8*>(ep + g * 8 + ks * 32);
            eq[ct] = *reinterpret_cast<const f32x4*>(&esq[cw + q * 64 + ct * 16 + g * 4]);
        }
        #pragma unroll
        for (int rt = 0; rt < 8; ++rt) {
            #pragma unroll
            for (int ct = 0; ct < 4; ++ct) {
                f32x4 acc = {0.f, 0.f, 0.f, 0.f};
                acc = __builtin_amdgcn_mfma_f32_16x16x32_bf16(efr[ct][0], zfr[rt][0], acc, 0, 0, 0);
                acc = __builtin_amdgcn_mfma_f32_16x16x32_bf16(efr[ct][1], zfr[rt][1], acc, 0, 0, 0);
                const float d0 = __fmaf_rn(-2.f, acc[0], eq[ct][0]);
                const float d1 = __fmaf_rn(-2.f, acc[1], eq[ct][1]);
                const float d2 = __fmaf_rn(-2.f, acc[2], eq[ct][2]);
                const float d3 = __fmaf_rn(-2.f, acc[3], eq[ct][3]);
                mrun[rt] = fminf(mrun[rt],
                                 fminf(fminf(d0, d1), fminf(d2, d3)));
            }
        }
    }
    #pragma unroll
    for (int rt = 0; rt < 8; ++rt)
        atomicMin(&rowmin[rt * 16 + ln], enc_f32(mrun[rt]));
    __syncthreads();

    // ---------- phase B: identical rescan, push candidates ----------
    float cthr[8];
    #pragma unroll
    for (int rt = 0; rt < 8; ++rt) {
        const int row = rt * 16 + ln;
        cthr[rt] = dec_f32(rowmin[row]) + thr[row];
    }
    #pragma unroll 1
    for (int q = 0; q < 4; ++q) {
        s16x8 efr[4][2];
        f32x4 eq[4];
        #pragma unroll
        for (int ct = 0; ct < 4; ++ct) {
            const int code = cw + q * 64 + ct * 16 + ln;
            const unsigned short* ep = ebf + code * 64;
            #pragma unroll
            for (int ks = 0; ks < 2; ++ks)
                efr[ct][ks] = *reinterpret_cast<const s16x8*>(ep + g * 8 + ks * 32);
            eq[ct] = *reinterpret_cast<const f32x4*>(&esq[cw + q * 64 + ct * 16 + g * 4]);
        }
        #pragma unroll
        for (int rt = 0; rt < 8; ++rt) {
            #pragma unroll
            for (int ct = 0; ct < 4; ++ct) {
                f32x4 acc = {0.f, 0.f, 0.f, 0.f};
                acc = __builtin_amdgcn_mfma_f32_16x16x32_bf16(efr[ct][0], zfr[rt][0], acc, 0, 0, 0);
                acc = __builtin_amdgcn_mfma_f32_16x16x32_bf16(efr[ct][1], zfr[rt][1], acc, 0, 0, 0);
                const int row  = rt * 16 + ln;
                const int cbas = cw + q * 64 + ct * 16 + g * 4;  // D-row m = g*4+reg
                #pragma unroll
                for (int rr = 0; rr < 4; ++rr) {
                    const float dd = __fmaf_rn(-2.f, acc[rr], eq[ct][rr]);
                    if (dd <= cthr[rt]) {
                        const unsigned idx = atomicAdd(&qcnt, 1u);
                        if (idx < (unsigned)QMAX)
                            queue[idx] = ((unsigned)row << 10) | (unsigned)(cbas + rr);
                    }
                }
            }
        }
    }
    __syncthreads();

    // ---------- phase C: exact rescore (R1 chain, bit-identical) ----------
    const unsigned qtot = qcnt;
    if (qtot <= (unsigned)QMAX) {
        for (unsigned i = t; i < qtot; i += TPB) {
            const unsigned pk = queue[i];
            const int row = (int)(pk >> 10);
            const int j   = (int)(pk & 1023u);
            const int swz = (row & 7) << 2;
            const float* e = emb + j * CDIM;
            float acc = 0.0f;
            #pragma unroll
            for (int k = 0; k < CDIM; ++k)
                acc = __fmaf_rn(zf[(row << 6) | (k ^ swz)], e[k], acc);
            const float d = __fmaf_rn(-2.f, acc, __fadd_rn(zsq[row], esq[j]));
            const unsigned long long key =
                ((unsigned long long)enc_f32(d) << 32) | (unsigned)j;
            atomicMin(&keys[row], key);          // (d asc, then j asc)
        }
    } else {
        // queue overflowed (never expected): provably-correct full rescan
        for (int i = t; i < RPB * N_EMB; i += TPB) {
            const int row = i >> 10;
            const int j   = i & 1023;
            const int swz = (row & 7) << 2;
            const float* e = emb + j * CDIM;
            float acc = 0.0f;
            #pragma unroll
            for (int k = 0; k < CDIM; ++k)
                acc = __fmaf_rn(zf[(row << 6) | (k ^ swz)], e[k], acc);
            const float d = __fmaf_rn(-2.f, acc, __fadd_rn(zsq[row], esq[j]));
            const unsigned long long key =
                ((unsigned long long)enc_f32(d) << 32) | (unsigned)j;
            atomicMin(&keys[row], key);
        }
    }
    __syncthreads();

    // ---------- output: gather emb[jmin] -> (b, c, s) ----------
    {
        const int row = t & 127;
        const int h   = t >> 7;              // c-half
        int jm = (int)(keys[row] & 0xFFFFFFFFull);
        if ((unsigned)jm >= (unsigned)N_EMB) jm = 0;   // safety
        const float* e = emb + (size_t)jm * CDIM + h * 32;
        float* op = out + (size_t)b * CDIM * SEQ + s0 + row;
        #pragma unroll
        for (int c = 0; c < 32; c += 4) {
            const f32x4 v = *reinterpret_cast<const f32x4*>(e + c);
            op[(size_t)(h * 32 + c + 0) * SEQ] = v[0];
            op[(size_t)(h * 32 + c + 1) * SEQ] = v[1];
            op[(size_t)(h * 32 + c + 2) * SEQ] = v[2];
            op[(size_t)(h * 32 + c + 3) * SEQ] = v[3];
        }
    }
}

// ---------------- fallback (R1, known-correct, 439 us) ----------------
__global__ __launch_bounds__(256, 2) void vq_fallback(
    const float* __restrict__ z, const float* __restrict__ emb,
    float* __restrict__ out)
{
    __shared__ float esq[N_EMB];
    for (int j = threadIdx.x; j < N_EMB; j += 256) {
        const float* e = emb + j * CDIM;
        float r[8];
        #pragma unroll
        for (int q = 0; q < 8; ++q) r[q] = __fmul_rn(e[q], e[q]);
        #pragma unroll
        for (int i = 8; i < 64; i += 8)
            #pragma unroll
            for (int q = 0; q < 8; ++q)
                r[q] = __fadd_rn(r[q], __fmul_rn(e[i + q], e[i + q]));
        esq[j] = pair8(r);
    }
    __syncthreads();
    const int row = blockIdx.x * 256 + threadIdx.x;
    const int b = row >> 12, s = row & (SEQ - 1);
    const float* zp = z + (size_t)b * CDIM * SEQ + s;
    float zv[CDIM];
    #pragma unroll
    for (int k = 0; k < CDIM; ++k) zv[k] = zp[(size_t)k * SEQ];
    float r[8];
    #pragma unroll
    for (int q = 0; q < 8; ++q) r[q] = __fmul_rn(zv[q], zv[q]);
    #pragma unroll
    for (int i = 8; i < 64; i += 8)
        #pragma unroll
        for (int q = 0; q < 8; ++q)
            r[q] = __fadd_rn(r[q], __fmul_rn(zv[i + q], zv[i + q]));
    const float zsq = pair8(r);
    float dmin = INFINITY; int jmin = 0;
    #pragma unroll 1
    for (int j = 0; j < N_EMB; ++j) {
        const float* e = emb + j * CDIM;
        float acc = 0.0f;
        #pragma unroll
        for (int k = 0; k < CDIM; ++k) acc = __fmaf_rn(zv[k], e[k], acc);
        const float d = __fmaf_rn(-2.f, acc, __fadd_rn(zsq, esq[j]));
        if (d < dmin) { dmin = d; jmin = j; }
    }
    const f32x4* ej = reinterpret_cast<const f32x4*>(emb + (size_t)jmin * CDIM);
    float* op = out + (size_t)b * CDIM * SEQ + s;
    #pragma unroll
    for (int q = 0; q < 16; ++q) {
        const f32x4 v = ej[q];
        op[(size_t)(4 * q + 0) * SEQ] = v[0];
        op[(size_t)(4 * q + 1) * SEQ] = v[1];
        op[(size_t)(4 * q + 2) * SEQ] = v[2];
        op[(size_t)(4 * q + 3) * SEQ] = v[3];
    }
}

extern "C" void kernel_launch(void* const* d_in, const int* in_sizes, int n_in,
                              void* d_out, int out_size, void* d_ws, size_t ws_size,
                              hipStream_t stream)
{
    const float* z   = (const float*)d_in[0];
    const float* emb = (const float*)d_in[1];
    float* out = (float*)d_out;

    if (ws_size < WS_NEED || d_ws == nullptr) {
        vq_fallback<<<NROWS / 256, 256, 0, stream>>>(z, emb, out);
        return;
    }
    unsigned short* ebf = (unsigned short*)((char*)d_ws + WS_EBF);
    float* esqg  = (float*)((char*)d_ws + WS_ESQ);
    float* emaxp = (float*)((char*)d_ws + WS_EMAX);

    vq_setup<<<1, 1024, 0, stream>>>(emb, ebf, esqg, emaxp);
    vq_main<<<NROWS / RPB, TPB, 0, stream>>>(z, emb, ebf, esqg, emaxp, out);
}